// Round 11
// baseline (369.878 us; speedup 1.0000x reference)
//
#include <hip/hip_runtime.h>
#include <math.h>

#define BB 16
#define SS 512
#define INDIM 64
#define DMODEL 64
#define HID 256
#define FILT 32
#define TYY 256
#define TXX 287
#define NT 5
#define RIDGEF 0.01f
#define THRESHF 0.005f
#define GRAMN 1088              // per-(b,t): 1056 pitch-33 gram + 32 cross
#define GRAMTOT (BB * NT * GRAMN)   // 87040 floats
#define NBLK 448                // 1.75 blocks/CU: co-residency guaranteed at
                                // 2 blocks/CU (launch_bounds(256,2)) with margin

// Union of per-phase LDS layouts: allocation = max (19.3 KB), not sum.
union __align__(16) SharedU {
    struct {
        float fr[8][INDIM];
        float th4[8][HID];
        float ee4[4][DMODEL];
        float part4[4][4][DMODEL];
        float partk4[4][4][DMODEL];
        float wred[4][8][2];
    } m;
    struct {
        float qt[4 * DMODEL];
        float redm[4][4];
    } a;
    struct {
        float xs[288];          // offset 0, 16B aligned (float4 reads)
        float ys[256];          // offset 1152, 16B aligned
        float Gs[1056];
        float crossL[32];
        float wv[NT * 64];
        float wtot[NT];
        int sl[64];
        int nselS;
        int stS[NT];
        float redA[4][33];
        float redB[4][33];
    } g;
    struct {
        float Af[1056];
        float zs[FILT];
        float wt[FILT];
        float xsr[TXX + 1];
        float red[256];
    } s;
};

// Software grid barrier (G16 pattern: device-scope atomics + threadfence).
// Safe because all NBLK blocks are co-resident by capacity construction.
__device__ __forceinline__ void grid_barrier(int* bar2, int nblocks)
{
    __syncthreads();
    if (threadIdx.x == 0) {
        __threadfence();                       // release: publish phase writes
        if (atomicAdd(&bar2[0], 1) == nblocks - 1) {
            atomicExch(&bar2[1], 1);
        } else {
            while (atomicAdd(&bar2[1], 0) == 0) __builtin_amdgcn_s_sleep(8);
        }
        __threadfence();                       // acquire: invalidate stale L1
    }
    __syncthreads();
}

__global__ __launch_bounds__(256, 2) void k_fused(
    const float* __restrict__ fps, const float* __restrict__ x,
    const float* __restrict__ y, const int* __restrict__ steps,
    const float* __restrict__ W1, const float* __restrict__ b1,
    const float* __restrict__ gamma, const float* __restrict__ beta,
    const float* __restrict__ W2, const float* __restrict__ b2,
    const float* __restrict__ Wq, const float* __restrict__ bq,
    const float* __restrict__ Wk, const float* __restrict__ bk,
    float* __restrict__ e_out, float* __restrict__ alpha,
    float* __restrict__ q_out, float* __restrict__ kT_out,
    float* __restrict__ gram, int* __restrict__ ctrs, int* __restrict__ bars,
    float* __restrict__ out0)
{
    __shared__ SharedU su;
    const int tid = threadIdx.x;
    const int wid = tid >> 6, lane = tid & 63;

    // ======================= Phase 1: MLP (8 rows/unit) ====================
    for (int u = blockIdx.x; u < BB * SS / 8; u += NBLK) {
        const int row0 = u << 3;
        { int r = tid >> 6, i = tid & 63;
          su.m.fr[r][i]     = fps[(row0 + r) * INDIM + i];
          su.m.fr[r + 4][i] = fps[(row0 + r + 4) * INDIM + i]; }
        __syncthreads();

        float h[8];
        float b1v = b1[tid];
        #pragma unroll
        for (int r = 0; r < 8; ++r) h[r] = b1v;
        for (int i = 0; i < INDIM; ++i) {
            float w = W1[i * HID + tid];
            #pragma unroll
            for (int r = 0; r < 8; ++r) h[r] = fmaf(su.m.fr[r][i], w, h[r]);
        }

        float s1[8], s2[8];
        #pragma unroll
        for (int r = 0; r < 8; ++r) { s1[r] = h[r]; s2[r] = h[r] * h[r]; }
        #pragma unroll
        for (int off = 1; off < 64; off <<= 1) {
            #pragma unroll
            for (int r = 0; r < 8; ++r) {
                s1[r] += __shfl_xor(s1[r], off);
                s2[r] += __shfl_xor(s2[r], off);
            }
        }
        if (lane == 0) {
            #pragma unroll
            for (int r = 0; r < 8; ++r) { su.m.wred[wid][r][0] = s1[r]; su.m.wred[wid][r][1] = s2[r]; }
        }
        __syncthreads();
        float gm = gamma[tid], bt = beta[tid];
        #pragma unroll
        for (int r = 0; r < 8; ++r) {
            float t1 = su.m.wred[0][r][0] + su.m.wred[1][r][0] + su.m.wred[2][r][0] + su.m.wred[3][r][0];
            float t2 = su.m.wred[0][r][1] + su.m.wred[1][r][1] + su.m.wred[2][r][1] + su.m.wred[3][r][1];
            float mu = t1 * (1.0f / HID);
            float var = t2 * (1.0f / HID) - mu * mu;
            float hn = (h[r] - mu) * rsqrtf(var + 1e-5f) * gm + bt;
            su.m.th4[r][tid] = tanhf(hn);
        }
        __syncthreads();

        #pragma unroll
        for (int half = 0; half < 2; ++half) {
            const int rbase = half * 4;
            { int p = tid >> 6, j = tid & 63;
              float acc[4] = {0.f, 0.f, 0.f, 0.f};
              for (int i = p * 64; i < p * 64 + 64; ++i) {
                  float w = W2[i * DMODEL + j];
                  #pragma unroll
                  for (int r = 0; r < 4; ++r) acc[r] = fmaf(su.m.th4[rbase + r][i], w, acc[r]);
              }
              #pragma unroll
              for (int r = 0; r < 4; ++r) su.m.part4[p][r][j] = acc[r];
            }
            __syncthreads();
            { int r = tid >> 6, j = tid & 63;
              float e = su.m.part4[0][r][j] + su.m.part4[1][r][j] + su.m.part4[2][r][j] + su.m.part4[3][r][j] + b2[j];
              float eo = tanhf(e);
              int row = row0 + rbase + r;
              int s = row & (SS - 1);
              e_out[(size_t)row * DMODEL + j] = eo;
              float div = expf(-(float)(j & ~1) * 0.14391156831212787f);  // ln(10000)/64
              float ang = (float)s * div;
              float pe = (j & 1) ? cosf(ang) : sinf(ang);
              su.m.ee4[r][j] = eo + 0.05f * pe;
            }
            __syncthreads();
            { int p = tid >> 6, j = tid & 63;
              float aq[4] = {0.f,0.f,0.f,0.f}, ak[4] = {0.f,0.f,0.f,0.f};
              for (int i = p * 16; i < p * 16 + 16; ++i) {
                  float wqv = Wq[i * DMODEL + j];
                  float wkv = Wk[i * DMODEL + j];
                  #pragma unroll
                  for (int r = 0; r < 4; ++r) {
                      aq[r] = fmaf(su.m.ee4[r][i], wqv, aq[r]);
                      ak[r] = fmaf(su.m.ee4[r][i], wkv, ak[r]);
                  }
              }
              #pragma unroll
              for (int r = 0; r < 4; ++r) { su.m.part4[p][r][j] = aq[r]; su.m.partk4[p][r][j] = ak[r]; }
            }
            __syncthreads();
            { int r = tid >> 6, j = tid & 63;
              float qv = su.m.part4[0][r][j] + su.m.part4[1][r][j] + su.m.part4[2][r][j] + su.m.part4[3][r][j] + bq[j];
              float kv = su.m.partk4[0][r][j] + su.m.partk4[1][r][j] + su.m.partk4[2][r][j] + su.m.partk4[3][r][j] + bk[j];
              int row = row0 + rbase + r;
              int b = row >> 9, s = row & (SS - 1);
              q_out[(size_t)row * DMODEL + j] = qv;
              kT_out[(size_t)(b * DMODEL + j) * SS + s] = kv;
            }
            __syncthreads();
        }
    }
    grid_barrier(bars + 0, NBLK);

    // ======================= Phase 2: attention ============================
    for (int u = blockIdx.x; u < BB * (SS / 4); u += NBLK) {
        const int b = u >> 7;
        const int t0 = (u & 127) << 2;
        const int t3 = t0 + 3;

        su.a.qt[tid] = q_out[(size_t)(b * SS + t0 + (tid >> 6)) * DMODEL + (tid & 63)];
        __syncthreads();

        const float* kTb = kT_out + (size_t)b * DMODEL * SS;
        const int s0 = tid, s1 = tid + 256;
        float a0[4] = {0,0,0,0}, a1[4] = {0,0,0,0};
        if (s1 <= t3) {
            for (int d = 0; d < DMODEL; ++d) {
                float k0 = kTb[d * SS + s0];
                float k1 = kTb[d * SS + s1];
                #pragma unroll
                for (int r = 0; r < 4; ++r) {
                    float qv = su.a.qt[r * DMODEL + d];
                    a0[r] = fmaf(qv, k0, a0[r]);
                    a1[r] = fmaf(qv, k1, a1[r]);
                }
            }
        } else if (s0 <= t3) {
            for (int d = 0; d < DMODEL; ++d) {
                float k0 = kTb[d * SS + s0];
                #pragma unroll
                for (int r = 0; r < 4; ++r) a0[r] = fmaf(su.a.qt[r * DMODEL + d], k0, a0[r]);
            }
        }
        float lg0[4], lg1[4];
        #pragma unroll
        for (int r = 0; r < 4; ++r) {
            int tr = t0 + r;
            lg0[r] = (s0 <= tr) ? 0.25f * a0[r] : -INFINITY;
            lg1[r] = (s1 <= tr) ? 0.25f * a1[r] : -INFINITY;
        }
        float mr[4];
        #pragma unroll
        for (int r = 0; r < 4; ++r) {
            float m = fmaxf(lg0[r], lg1[r]);
            #pragma unroll
            for (int off = 32; off > 0; off >>= 1) m = fmaxf(m, __shfl_xor(m, off));
            if (lane == 0) su.a.redm[r][wid] = m;
        }
        __syncthreads();
        #pragma unroll
        for (int r = 0; r < 4; ++r)
            mr[r] = fmaxf(fmaxf(su.a.redm[r][0], su.a.redm[r][1]),
                          fmaxf(su.a.redm[r][2], su.a.redm[r][3]));
        __syncthreads();
        float ex0[4], ex1[4], sr[4];
        #pragma unroll
        for (int r = 0; r < 4; ++r) {
            ex0[r] = expf(lg0[r] - mr[r]);
            ex1[r] = expf(lg1[r] - mr[r]);
            float sm = ex0[r] + ex1[r];
            #pragma unroll
            for (int off = 32; off > 0; off >>= 1) sm += __shfl_xor(sm, off);
            if (lane == 0) su.a.redm[r][wid] = sm;
        }
        __syncthreads();
        #pragma unroll
        for (int r = 0; r < 4; ++r)
            sr[r] = su.a.redm[r][0] + su.a.redm[r][1] + su.a.redm[r][2] + su.a.redm[r][3];
        #pragma unroll
        for (int r = 0; r < 4; ++r) {
            float inv = 1.0f / sr[r];
            size_t base = (size_t)(b * SS + t0 + r) * SS;
            alpha[base + s0] = ex0[r] * inv;
            alpha[base + s1] = ex1[r] * inv;
        }
        __syncthreads();
    }
    grid_barrier(bars + 2, NBLK);

    // ======================= Phase 3: gram partials ========================
    const int C = 64, CS = SS / 64;
    for (int u = blockIdx.x; u < BB * C; u += NBLK) {
        const int b = u / C;
        const int chunk = u % C;

        if (tid < NT) su.g.stS[tid] = steps[tid];
        if (tid < 32) su.g.Gs[tid * 33 + 32] = 0.f;
        __syncthreads();

        for (int idx = tid; idx < NT * CS; idx += 256) {
            int t = idx / CS, si = idx % CS;
            float a = alpha[(size_t)(b * SS + su.g.stS[t]) * SS + chunk * CS + si];
            su.g.wv[t * 64 + si] = (a > THRESHF) ? a : 0.f;
        }
        __syncthreads();
        if (tid < NT) {
            float s = 0.f;
            for (int si = 0; si < CS; ++si) s += su.g.wv[tid * 64 + si];
            su.g.wtot[tid] = s;
        }
        if (wid == 0) {
            float m = 0.f;
            if (lane < CS)
                m = su.g.wv[lane] + su.g.wv[64 + lane] + su.g.wv[128 + lane]
                  + su.g.wv[192 + lane] + su.g.wv[256 + lane];
            unsigned long long mask = __ballot(m > 0.f);
            if (m > 0.f) {
                int pos = __popcll(mask & ((1ull << lane) - 1ull));
                su.g.sl[pos] = lane;
            }
            if (lane == 0) su.g.nselS = __popcll(mask);
        }
        __syncthreads();
        const int nsel = su.g.nselS;

        float acc[NT][5];
        #pragma unroll
        for (int t = 0; t < NT; ++t) {
            #pragma unroll
            for (int r = 0; r < 5; ++r) acc[t][r] = 0.f;
        }

        float rx0 = 0.f, rx1 = 0.f, ry = 0.f;
        if (nsel > 0) {
            int sg = chunk * CS + su.g.sl[0];
            const float* xr = x + (size_t)(b * SS + sg) * TXX;
            const float* yr = y + (size_t)(b * SS + sg) * TYY;
            rx0 = xr[tid];
            if (tid < 31) rx1 = xr[256 + tid];
            ry = yr[tid];
        }

        for (int i = 0; i < nsel; ++i) {
            su.g.xs[tid] = rx0;
            if (tid < 31) su.g.xs[256 + tid] = rx1;
            su.g.ys[tid] = ry;
            const int sl_cur = su.g.sl[i];
            __syncthreads();

            if (i + 1 < nsel) {
                int sg = chunk * CS + su.g.sl[i + 1];
                const float* xr = x + (size_t)(b * SS + sg) * TXX;
                const float* yr = y + (size_t)(b * SS + sg) * TYY;
                rx0 = xr[tid];
                if (tid < 31) rx1 = xr[256 + tid];
                ry = yr[tid];
            }

            { int l = tid & 31, p = tid >> 5;
              const float4* xk4 = (const float4*)(su.g.xs + (p << 5));
              const float4* yk4 = (const float4*)(su.g.ys + (p << 5));
              float c = 0.f, a = 0.f;
              #pragma unroll
              for (int j = 0; j < 8; ++j) {
                  float4 xk = xk4[j];
                  float4 yk = yk4[j];
                  int kb = (p << 5) + (j << 2);
                  float x0 = su.g.xs[kb + l],     x1 = su.g.xs[kb + 1 + l];
                  float x2 = su.g.xs[kb + 2 + l], x3 = su.g.xs[kb + 3 + l];
                  c = fmaf(x0, yk.x, c); a = fmaf(xk.x, x0, a);
                  c = fmaf(x1, yk.y, c); a = fmaf(xk.y, x1, a);
                  c = fmaf(x2, yk.z, c); a = fmaf(xk.z, x2, a);
                  c = fmaf(x3, yk.w, c); a = fmaf(xk.w, x3, a);
              }
              c += __shfl_xor(c, 32);
              a += __shfl_xor(a, 32);
              if (lane < 32) { su.g.redA[wid][l] = c; su.g.redB[wid][l] = a; }
            }
            __syncthreads();

            if (tid < 32)
                su.g.crossL[tid] = su.g.redA[0][tid] + su.g.redA[1][tid]
                                 + su.g.redA[2][tid] + su.g.redA[3][tid];

            { int jj = lane & 31;
              #pragma unroll
              for (int pass = 0; pass < 4; ++pass) {
                  int dd = 2 * (wid + 4 * pass) + (lane >> 5);
                  float g0 = su.g.redB[0][dd] + su.g.redB[1][dd]
                           + su.g.redB[2][dd] + su.g.redB[3][dd];
                  float dlt = 0.f;
                  if (jj > 0 && jj + dd < 32)
                      dlt = su.g.xs[jj + 255] * su.g.xs[jj + 255 + dd]
                          - su.g.xs[jj - 1] * su.g.xs[jj - 1 + dd];
                  #pragma unroll
                  for (int off = 1; off < 32; off <<= 1) {
                      float tsh = __shfl_up(dlt, off, 32);
                      if (jj >= off) dlt += tsh;
                  }
                  if (jj + dd < 32) {
                      float gval = g0 + dlt;
                      su.g.Gs[jj * 33 + jj + dd] = gval;
                      su.g.Gs[(jj + dd) * 33 + jj] = gval;
                  }
              }
            }
            __syncthreads();

            { float g0 = su.g.Gs[tid], g1 = su.g.Gs[tid + 256];
              float g2 = su.g.Gs[tid + 512], g3 = su.g.Gs[tid + 768];
              float g4 = (tid < 32) ? su.g.Gs[1024 + tid]
                       : ((tid < 64) ? su.g.crossL[tid - 32] : 0.f);
              #pragma unroll
              for (int t = 0; t < NT; ++t) {
                  float w = su.g.wv[t * 64 + sl_cur];
                  if (w > 0.f) {
                      acc[t][0] = fmaf(w, g0, acc[t][0]);
                      acc[t][1] = fmaf(w, g1, acc[t][1]);
                      acc[t][2] = fmaf(w, g2, acc[t][2]);
                      acc[t][3] = fmaf(w, g3, acc[t][3]);
                      acc[t][4] = fmaf(w, g4, acc[t][4]);
                  }
              }
            }
        }

        #pragma unroll
        for (int t = 0; t < NT; ++t) {
            if (su.g.wtot[t] > 0.f) {
                float* gr = gram + (size_t)(b * NT + t) * GRAMN;
                #pragma unroll
                for (int r = 0; r < 4; ++r) atomicAdd(&gr[tid + 256 * r], acc[t][r]);
                if (tid < 64) atomicAdd(&gr[1024 + tid], acc[t][4]);
            }
        }
        __syncthreads();
    }
    grid_barrier(bars + 4, NBLK);

    // ======================= Phase 4: solve + loss =========================
    for (int g = blockIdx.x; g < BB * NT; g += NBLK) {
        const int b = g / NT, t = g % NT;
        const int step_s = steps[t];

        const float* row = gram + (size_t)g * GRAMN;
        su.s.Af[tid] = row[tid];
        su.s.Af[tid + 256] = row[tid + 256];
        su.s.Af[tid + 512] = row[tid + 512];
        su.s.Af[tid + 768] = row[tid + 768];
        if (tid < 32) su.s.Af[1024 + tid] = row[1024 + tid];
        else if (tid < 64) su.s.zs[tid - 32] = row[1024 + tid];

        int anyv = 0;
        { const float* arow = alpha + (size_t)(b * SS + step_s) * SS;
          anyv = (arow[tid] > THRESHF || arow[tid + 256] > THRESHF) ? 1 : 0;
          #pragma unroll
          for (int off = 32; off > 0; off >>= 1) anyv |= __shfl_xor(anyv, off);
          if (lane == 0) su.s.red[wid] = (float)anyv; }
        __syncthreads();
        anyv = (su.s.red[0] + su.s.red[1] + su.s.red[2] + su.s.red[3]) > 0.f;
        if (tid < 32) su.s.Af[tid * 33 + tid] += RIDGEF;
        __syncthreads();

        // single-wave register Cholesky + shuffle triangular solves
        if (tid < 32) {
            float a[32];
            #pragma unroll
            for (int j = 0; j < 32; ++j) a[j] = su.s.Af[tid * 33 + j];
            #pragma unroll
            for (int k = 0; k < 32; ++k) {
                float akk = __shfl(a[k], k);
                float dk = sqrtf(akk);
                float ck = a[k] / dk;
                if (tid >= k) a[k] = ck;
                #pragma unroll
                for (int m = k + 1; m < 32; ++m) {
                    float cm = __shfl(ck, m);
                    if (tid >= m) a[m] = fmaf(-ck, cm, a[m]);
                }
            }
            #pragma unroll
            for (int j = 0; j < 32; ++j)
                if (j <= tid) su.s.Af[tid * 33 + j] = a[j];

            float zl = su.s.zs[tid];
            #pragma unroll
            for (int k = 0; k < 32; ++k) {
                float akk = __shfl(a[k], k);
                float zk = __shfl(zl, k) / akk;
                if (tid == k) zl = zk;
                else if (tid > k) zl = fmaf(-a[k], zk, zl);
            }
            #pragma unroll
            for (int k = 31; k >= 0; --k) {
                float akk = __shfl(a[k], k);
                float wk = __shfl(zl, k) / akk;
                if (tid == k) zl = wk;
                else if (tid < k) zl = fmaf(-su.s.Af[k * 33 + tid], wk, zl);
            }
            su.s.wt[tid] = zl;
        }
        __syncthreads();

        const float* xrow = x + (size_t)(b * SS + step_s) * TXX;
        for (int i = tid; i < TXX; i += 256) su.s.xsr[i] = xrow[i];
        __syncthreads();
        float pk = 0.f;
        #pragma unroll
        for (int l = 0; l < FILT; ++l) pk = fmaf(su.s.xsr[tid + l], su.s.wt[l], pk);
        float d = y[(size_t)(b * SS + step_s) * TYY + tid] - pk;
        su.s.red[tid] = d * d;
        __syncthreads();
        for (int off = 128; off > 0; off >>= 1) {
            if (tid < off) su.s.red[tid] += su.s.red[tid + off];
            __syncthreads();
        }
        if (tid == 0) {
            float lossval = su.s.red[0] * (1.0f / TYY);
            float* loss_sum = (float*)(ctrs + 2);
            if (anyv) {
                atomicAdd(loss_sum, lossval);
                atomicAdd(&ctrs[1], 1);
            }
            __threadfence();
            int prev = atomicAdd(&ctrs[0], 1);
            if (prev == BB * NT - 1) {
                float s = atomicAdd(loss_sum, 0.0f);   // atomic read
                int c = atomicAdd(&ctrs[1], 0);
                out0[0] = s / (float)(c > 0 ? c : 1);
            }
        }
        __syncthreads();
    }
}

extern "C" void kernel_launch(void* const* d_in, const int* in_sizes, int n_in,
                              void* d_out, int out_size, void* d_ws, size_t ws_size,
                              hipStream_t stream)
{
    const float* fps  = (const float*)d_in[0];
    const float* x    = (const float*)d_in[1];
    const float* y    = (const float*)d_in[2];
    const int* steps  = (const int*)d_in[3];
    const float* W1   = (const float*)d_in[4];
    const float* b1   = (const float*)d_in[5];
    const float* gamma= (const float*)d_in[6];
    const float* beta = (const float*)d_in[7];
    const float* W2   = (const float*)d_in[8];
    const float* b2   = (const float*)d_in[9];
    const float* Wq   = (const float*)d_in[10];
    const float* bq   = (const float*)d_in[11];
    const float* Wk   = (const float*)d_in[12];
    const float* bk   = (const float*)d_in[13];

    // Output f32 flat: [loss(1) | alpha(B*S*S) | e_orig(B*S*D)]
    float* out   = (float*)d_out;
    float* alpha = out + 1;
    float* e_out = out + 1 + (size_t)BB * SS * SS;

    // ws: [gram(87040 f) | ctrs(4 i) | bars(8 i) | pad | q | kT]
    float* gram = (float*)d_ws;
    int*   ctrs = (int*)(gram + GRAMTOT);
    int*   bars = ctrs + 4;
    float* q    = (float*)d_ws + GRAMTOT + 16;     // 16B-aligned
    float* kT   = q + (size_t)BB * SS * DMODEL;

    // zero gram + ctrs + barrier state in one stream-ordered memset
    hipMemsetAsync(gram, 0, (size_t)GRAMTOT * 4 + 64, stream);

    hipLaunchKernelGGL(k_fused, dim3(NBLK), dim3(256), 0, stream,
                       fps, x, y, steps, W1, b1, gamma, beta, W2, b2,
                       Wq, bq, Wk, bk, e_out, alpha, q, kT,
                       gram, ctrs, bars, out);
}

// Round 12
// 193.000 us; speedup vs baseline: 1.9165x; 1.9165x over previous
//
#include <hip/hip_runtime.h>
#include <math.h>

#define BB 16
#define SS 512
#define INDIM 64
#define DMODEL 64
#define HID 256
#define FILT 32
#define TYY 256
#define TXX 287
#define NT 5
#define RIDGEF 0.01f
#define THRESHF 0.005f
#define GRAMN 1088              // per-(b,t): 1056 pitch-33 gram + 32 cross
#define GRAMTOT (BB * NT * GRAMN)   // 87040 floats

// fast tanh: clamped exp2-path (v_exp_f32), |err| ~1e-6, no libcall
__device__ __forceinline__ float ftanh(float v)
{
    float vc = fminf(fmaxf(v, -15.f), 15.f);
    float e = __expf(2.f * vc);
    return (e - 1.f) / (e + 1.f);
}

// ---------------------------------------------------------------------------
// Kernel 1: fused MLP -> LN -> tanh -> W2 -> tanh (e_orig) -> +pos-enc -> q,kT.
// 8 rows/block.  Side-job: blocks 0..339 zero gram; block 340 zeros counters.
// ---------------------------------------------------------------------------
__global__ __launch_bounds__(256) void k_mlp(
    const float* __restrict__ fps, const float* __restrict__ W1, const float* __restrict__ b1,
    const float* __restrict__ gamma, const float* __restrict__ beta,
    const float* __restrict__ W2, const float* __restrict__ b2,
    const float* __restrict__ Wq, const float* __restrict__ bq,
    const float* __restrict__ Wk, const float* __restrict__ bk,
    float* __restrict__ e_out, float* __restrict__ q_out, float* __restrict__ kT_out,
    float* __restrict__ gram, int* __restrict__ ctrs)
{
    const int row0 = blockIdx.x << 3;
    const int tid = threadIdx.x;
    const int wid = tid >> 6, lane = tid & 63;

    if (blockIdx.x < GRAMTOT / 256) {
        gram[(size_t)blockIdx.x * 256 + tid] = 0.f;
    } else if (blockIdx.x == GRAMTOT / 256 && tid < 4) {
        ctrs[tid] = 0;   // [0]=done_ctr [1]=valid_cnt [2]=loss_sum bits [3]=pad
    }

    __shared__ float fr[8][INDIM];
    __shared__ float th4[8][HID];
    __shared__ float ee4[4][DMODEL];
    __shared__ float part4[4][4][DMODEL];
    __shared__ float partk4[4][4][DMODEL];
    __shared__ float wred[4][8][2];

    { int r = tid >> 6, i = tid & 63;
      fr[r][i]     = fps[(row0 + r) * INDIM + i];
      fr[r + 4][i] = fps[(row0 + r + 4) * INDIM + i]; }
    __syncthreads();

    float h[8];
    float b1v = b1[tid];
    #pragma unroll
    for (int r = 0; r < 8; ++r) h[r] = b1v;
    for (int i = 0; i < INDIM; ++i) {
        float w = W1[i * HID + tid];
        #pragma unroll
        for (int r = 0; r < 8; ++r) h[r] = fmaf(fr[r][i], w, h[r]);
    }

    float s1[8], s2[8];
    #pragma unroll
    for (int r = 0; r < 8; ++r) { s1[r] = h[r]; s2[r] = h[r] * h[r]; }
    #pragma unroll
    for (int off = 1; off < 64; off <<= 1) {
        #pragma unroll
        for (int r = 0; r < 8; ++r) {
            s1[r] += __shfl_xor(s1[r], off);
            s2[r] += __shfl_xor(s2[r], off);
        }
    }
    if (lane == 0) {
        #pragma unroll
        for (int r = 0; r < 8; ++r) { wred[wid][r][0] = s1[r]; wred[wid][r][1] = s2[r]; }
    }
    __syncthreads();
    float gm = gamma[tid], bt = beta[tid];
    #pragma unroll
    for (int r = 0; r < 8; ++r) {
        float t1 = wred[0][r][0] + wred[1][r][0] + wred[2][r][0] + wred[3][r][0];
        float t2 = wred[0][r][1] + wred[1][r][1] + wred[2][r][1] + wred[3][r][1];
        float mu = t1 * (1.0f / HID);
        float var = t2 * (1.0f / HID) - mu * mu;
        float hn = (h[r] - mu) * rsqrtf(var + 1e-5f) * gm + bt;
        th4[r][tid] = ftanh(hn);
    }
    __syncthreads();

    #pragma unroll
    for (int half = 0; half < 2; ++half) {
        const int rbase = half * 4;
        { int p = tid >> 6, j = tid & 63;
          float acc[4] = {0.f, 0.f, 0.f, 0.f};
          for (int i = p * 64; i < p * 64 + 64; ++i) {
              float w = W2[i * DMODEL + j];
              #pragma unroll
              for (int r = 0; r < 4; ++r) acc[r] = fmaf(th4[rbase + r][i], w, acc[r]);
          }
          #pragma unroll
          for (int r = 0; r < 4; ++r) part4[p][r][j] = acc[r];
        }
        __syncthreads();
        { int r = tid >> 6, j = tid & 63;
          float e = part4[0][r][j] + part4[1][r][j] + part4[2][r][j] + part4[3][r][j] + b2[j];
          float eo = ftanh(e);
          int row = row0 + rbase + r;
          int s = row & (SS - 1);
          e_out[(size_t)row * DMODEL + j] = eo;
          float div = __expf(-(float)(j & ~1) * 0.14391156831212787f);  // ln(10000)/64
          float ang = (float)s * div;
          float pe = (j & 1) ? __cosf(ang) : __sinf(ang);
          ee4[r][j] = eo + 0.05f * pe;
        }
        __syncthreads();
        { int p = tid >> 6, j = tid & 63;
          float aq[4] = {0.f,0.f,0.f,0.f}, ak[4] = {0.f,0.f,0.f,0.f};
          for (int i = p * 16; i < p * 16 + 16; ++i) {
              float wqv = Wq[i * DMODEL + j];
              float wkv = Wk[i * DMODEL + j];
              #pragma unroll
              for (int r = 0; r < 4; ++r) {
                  aq[r] = fmaf(ee4[r][i], wqv, aq[r]);
                  ak[r] = fmaf(ee4[r][i], wkv, ak[r]);
              }
          }
          #pragma unroll
          for (int r = 0; r < 4; ++r) { part4[p][r][j] = aq[r]; partk4[p][r][j] = ak[r]; }
        }
        __syncthreads();
        { int r = tid >> 6, j = tid & 63;
          float qv = part4[0][r][j] + part4[1][r][j] + part4[2][r][j] + part4[3][r][j] + bq[j];
          float kv = partk4[0][r][j] + partk4[1][r][j] + partk4[2][r][j] + partk4[3][r][j] + bk[j];
          int row = row0 + rbase + r;
          int b = row >> 9, s = row & (SS - 1);
          q_out[(size_t)row * DMODEL + j] = qv;
          kT_out[(size_t)(b * DMODEL + j) * SS + s] = kv;
        }
        __syncthreads();
    }
}

// ---------------------------------------------------------------------------
// Kernel 2: causal scores + softmax -> alpha f32 into d_out.
// 8 t-rows per block: kT panel L2 reads amortized 8x (was 4x).
// ---------------------------------------------------------------------------
__global__ __launch_bounds__(256) void k_attn(
    const float* __restrict__ q, const float* __restrict__ kT,
    float* __restrict__ alpha)
{
    const int blk = blockIdx.x;
    const int b = blk >> 6;              // 64 blocks per batch
    const int t0 = (blk & 63) << 3;
    const int t7 = t0 + 7;
    const int tid = threadIdx.x;
    const int wave = tid >> 6, lane = tid & 63;

    __shared__ float qt[8 * DMODEL];
    __shared__ float redm[8][4];

    { size_t qb = (size_t)(b * SS + t0) * DMODEL;
      qt[tid] = q[qb + tid];
      qt[tid + 256] = q[qb + tid + 256]; }
    __syncthreads();

    const float* kTb = kT + (size_t)b * DMODEL * SS;
    const int s0 = tid, s1 = tid + 256;
    float a0[8] = {0,0,0,0,0,0,0,0}, a1[8] = {0,0,0,0,0,0,0,0};
    if (t7 >= 256) {
        for (int d = 0; d < DMODEL; ++d) {
            float k0 = kTb[d * SS + s0];
            float k1 = kTb[d * SS + s1];
            #pragma unroll
            for (int r = 0; r < 8; ++r) {
                float qv = qt[r * DMODEL + d];
                a0[r] = fmaf(qv, k0, a0[r]);
                a1[r] = fmaf(qv, k1, a1[r]);
            }
        }
    } else {
        for (int d = 0; d < DMODEL; ++d) {
            float k0 = kTb[d * SS + s0];
            #pragma unroll
            for (int r = 0; r < 8; ++r)
                a0[r] = fmaf(qt[r * DMODEL + d], k0, a0[r]);
        }
    }
    float lg0[8], lg1[8];
    #pragma unroll
    for (int r = 0; r < 8; ++r) {
        int tr = t0 + r;
        lg0[r] = (s0 <= tr) ? 0.25f * a0[r] : -INFINITY;
        lg1[r] = (s1 <= tr) ? 0.25f * a1[r] : -INFINITY;
    }
    float mr[8];
    #pragma unroll
    for (int r = 0; r < 8; ++r) {
        float m = fmaxf(lg0[r], lg1[r]);
        #pragma unroll
        for (int off = 32; off > 0; off >>= 1) m = fmaxf(m, __shfl_xor(m, off));
        if (lane == 0) redm[r][wave] = m;
    }
    __syncthreads();
    #pragma unroll
    for (int r = 0; r < 8; ++r)
        mr[r] = fmaxf(fmaxf(redm[r][0], redm[r][1]), fmaxf(redm[r][2], redm[r][3]));
    __syncthreads();
    float ex0[8], ex1[8], sr[8];
    #pragma unroll
    for (int r = 0; r < 8; ++r) {
        ex0[r] = __expf(lg0[r] - mr[r]);   // exp(-inf) = 0 for masked
        ex1[r] = __expf(lg1[r] - mr[r]);
        float sm = ex0[r] + ex1[r];
        #pragma unroll
        for (int off = 32; off > 0; off >>= 1) sm += __shfl_xor(sm, off);
        if (lane == 0) redm[r][wave] = sm;
    }
    __syncthreads();
    #pragma unroll
    for (int r = 0; r < 8; ++r)
        sr[r] = redm[r][0] + redm[r][1] + redm[r][2] + redm[r][3];
    #pragma unroll
    for (int r = 0; r < 8; ++r) {
        float inv = 1.0f / sr[r];
        size_t base = (size_t)(b * SS + t0 + r) * SS;
        alpha[base + s0] = ex0[r] * inv;
        alpha[base + s1] = ex1[r] * inv;
    }
}

// ---------------------------------------------------------------------------
// Kernel 3: per (b, s-chunk); float4 dot loops, prefix-scan diagonals,
// register acc; ballot-compacted selection; atomicAdd into gram.
// ---------------------------------------------------------------------------
__global__ __launch_bounds__(256) void k_gpart(
    const float* __restrict__ x, const float* __restrict__ y,
    const int* __restrict__ steps, const float* __restrict__ alpha,
    float* __restrict__ gram, int C, int CS)
{
    const int b = blockIdx.x / C;
    const int chunk = blockIdx.x % C;
    const int tid = threadIdx.x;
    const int lane = tid & 63, wid = tid >> 6;

    __shared__ __align__(16) float xs[288];
    __shared__ __align__(16) float ys[256];
    __shared__ float Gs[1056];        // 32x33 (pitch 33)
    __shared__ float crossL[32];
    __shared__ float wv[NT * 64];
    __shared__ float wtot[NT];
    __shared__ int sl[64];
    __shared__ int nselS;
    __shared__ int stS[NT];
    __shared__ float redA[4][33];
    __shared__ float redB[4][33];

    if (tid < NT) stS[tid] = steps[tid];
    if (tid < 32) Gs[tid * 33 + 32] = 0.f;
    __syncthreads();

    for (int idx = tid; idx < NT * CS; idx += 256) {
        int t = idx / CS, si = idx % CS;
        float a = alpha[(size_t)(b * SS + stS[t]) * SS + chunk * CS + si];
        wv[t * 64 + si] = (a > THRESHF) ? a : 0.f;
    }
    __syncthreads();
    if (tid < NT) {
        float s = 0.f;
        for (int si = 0; si < CS; ++si) s += wv[tid * 64 + si];
        wtot[tid] = s;
    }
    if (wid == 0) {
        float m = 0.f;
        if (lane < CS)
            m = wv[lane] + wv[64 + lane] + wv[128 + lane] + wv[192 + lane] + wv[256 + lane];
        unsigned long long mask = __ballot(m > 0.f);
        if (m > 0.f) {
            int pos = __popcll(mask & ((1ull << lane) - 1ull));
            sl[pos] = lane;
        }
        if (lane == 0) nselS = __popcll(mask);
    }
    __syncthreads();
    const int nsel = nselS;

    float acc[NT][5];
    #pragma unroll
    for (int t = 0; t < NT; ++t) {
        #pragma unroll
        for (int r = 0; r < 5; ++r) acc[t][r] = 0.f;
    }

    float rx0 = 0.f, rx1 = 0.f, ry = 0.f;
    if (nsel > 0) {
        int sg = chunk * CS + sl[0];
        const float* xr = x + (size_t)(b * SS + sg) * TXX;
        const float* yr = y + (size_t)(b * SS + sg) * TYY;
        rx0 = xr[tid];
        if (tid < 31) rx1 = xr[256 + tid];
        ry = yr[tid];
    }

    for (int i = 0; i < nsel; ++i) {
        xs[tid] = rx0;
        if (tid < 31) xs[256 + tid] = rx1;
        ys[tid] = ry;
        const int sl_cur = sl[i];
        __syncthreads();

        if (i + 1 < nsel) {
            int sg = chunk * CS + sl[i + 1];
            const float* xr = x + (size_t)(b * SS + sg) * TXX;
            const float* yr = y + (size_t)(b * SS + sg) * TYY;
            rx0 = xr[tid];
            if (tid < 31) rx1 = xr[256 + tid];
            ry = yr[tid];
        }

        { int l = tid & 31, p = tid >> 5;
          const float4* xk4 = (const float4*)(xs + (p << 5));
          const float4* yk4 = (const float4*)(ys + (p << 5));
          float c = 0.f, a = 0.f;
          #pragma unroll
          for (int j = 0; j < 8; ++j) {
              float4 xk = xk4[j];
              float4 yk = yk4[j];
              int kb = (p << 5) + (j << 2);
              float x0 = xs[kb + l],     x1 = xs[kb + 1 + l];
              float x2 = xs[kb + 2 + l], x3 = xs[kb + 3 + l];
              c = fmaf(x0, yk.x, c); a = fmaf(xk.x, x0, a);
              c = fmaf(x1, yk.y, c); a = fmaf(xk.y, x1, a);
              c = fmaf(x2, yk.z, c); a = fmaf(xk.z, x2, a);
              c = fmaf(x3, yk.w, c); a = fmaf(xk.w, x3, a);
          }
          c += __shfl_xor(c, 32);
          a += __shfl_xor(a, 32);
          if (lane < 32) { redA[wid][l] = c; redB[wid][l] = a; }
        }
        __syncthreads();

        if (tid < 32)
            crossL[tid] = redA[0][tid] + redA[1][tid] + redA[2][tid] + redA[3][tid];

        { int jj = lane & 31;
          #pragma unroll
          for (int pass = 0; pass < 4; ++pass) {
              int dd = 2 * (wid + 4 * pass) + (lane >> 5);
              float g0 = redB[0][dd] + redB[1][dd] + redB[2][dd] + redB[3][dd];
              float dlt = 0.f;
              if (jj > 0 && jj + dd < 32)
                  dlt = xs[jj + 255] * xs[jj + 255 + dd]
                      - xs[jj - 1] * xs[jj - 1 + dd];
              #pragma unroll
              for (int off = 1; off < 32; off <<= 1) {
                  float tsh = __shfl_up(dlt, off, 32);
                  if (jj >= off) dlt += tsh;
              }
              if (jj + dd < 32) {
                  float gval = g0 + dlt;
                  Gs[jj * 33 + jj + dd] = gval;
                  Gs[(jj + dd) * 33 + jj] = gval;
              }
          }
        }
        __syncthreads();

        { float g0 = Gs[tid], g1 = Gs[tid + 256], g2 = Gs[tid + 512], g3 = Gs[tid + 768];
          float g4 = (tid < 32) ? Gs[1024 + tid]
                   : ((tid < 64) ? crossL[tid - 32] : 0.f);
          #pragma unroll
          for (int t = 0; t < NT; ++t) {
              float w = wv[t * 64 + sl_cur];
              if (w > 0.f) {
                  acc[t][0] = fmaf(w, g0, acc[t][0]);
                  acc[t][1] = fmaf(w, g1, acc[t][1]);
                  acc[t][2] = fmaf(w, g2, acc[t][2]);
                  acc[t][3] = fmaf(w, g3, acc[t][3]);
                  acc[t][4] = fmaf(w, g4, acc[t][4]);
              }
          }
        }
    }

    #pragma unroll
    for (int t = 0; t < NT; ++t) {
        if (wtot[t] > 0.f) {
            float* gr = gram + (size_t)(b * NT + t) * GRAMN;
            #pragma unroll
            for (int r = 0; r < 4; ++r) atomicAdd(&gr[tid + 256 * r], acc[t][r]);
            if (tid < 64) atomicAdd(&gr[1024 + tid], acc[t][4]);
        }
    }
}

// ---------------------------------------------------------------------------
// Kernel 4: per (b,t): gram row + ridge, single-wave register Cholesky,
// shuffle solves, prediction loss; masked-mean via atomics + last-block.
// ---------------------------------------------------------------------------
__global__ __launch_bounds__(256) void k_solve2(
    const float* __restrict__ x, const float* __restrict__ y,
    const int* __restrict__ steps, const float* __restrict__ alpha,
    const float* __restrict__ gram,
    int* __restrict__ ctrs, float* __restrict__ out0)
{
    const int g = blockIdx.x;
    const int b = g / NT, t = g % NT;
    const int tid = threadIdx.x;

    __shared__ float Af[1056];   // pitch 33
    __shared__ float zs[FILT];
    __shared__ float wt[FILT];
    __shared__ float xsr[TXX + 1];
    __shared__ float red[256];
    __shared__ int step_s;
    __shared__ int anyv;

    if (tid == 0) { step_s = steps[t]; anyv = 0; }
    __syncthreads();

    const float* row = gram + (size_t)g * GRAMN;
    Af[tid] = row[tid];
    Af[tid + 256] = row[tid + 256];
    Af[tid + 512] = row[tid + 512];
    Af[tid + 768] = row[tid + 768];
    if (tid < 32) Af[1024 + tid] = row[1024 + tid];
    else if (tid < 64) zs[tid - 32] = row[1024 + tid];

    { const float* arow = alpha + (size_t)(b * SS + step_s) * SS;
      if (arow[tid] > THRESHF || arow[tid + 256] > THRESHF) anyv = 1; }
    __syncthreads();
    if (tid < 32) Af[tid * 33 + tid] += RIDGEF;
    __syncthreads();

    if (tid < 32) {
        float a[32];
        #pragma unroll
        for (int j = 0; j < 32; ++j) a[j] = Af[tid * 33 + j];
        #pragma unroll
        for (int k = 0; k < 32; ++k) {
            float akk = __shfl(a[k], k);
            float dk = sqrtf(akk);
            float ck = a[k] / dk;
            if (tid >= k) a[k] = ck;
            #pragma unroll
            for (int m = k + 1; m < 32; ++m) {
                float cm = __shfl(ck, m);
                if (tid >= m) a[m] = fmaf(-ck, cm, a[m]);
            }
        }
        #pragma unroll
        for (int j = 0; j < 32; ++j)
            if (j <= tid) Af[tid * 33 + j] = a[j];

        float zl = zs[tid];
        #pragma unroll
        for (int k = 0; k < 32; ++k) {
            float akk = __shfl(a[k], k);
            float zk = __shfl(zl, k) / akk;
            if (tid == k) zl = zk;
            else if (tid > k) zl = fmaf(-a[k], zk, zl);
        }
        #pragma unroll
        for (int k = 31; k >= 0; --k) {
            float akk = __shfl(a[k], k);
            float wk = __shfl(zl, k) / akk;
            if (tid == k) zl = wk;
            else if (tid < k) zl = fmaf(-Af[k * 33 + tid], wk, zl);
        }
        wt[tid] = zl;
    }
    __syncthreads();

    const int sstep = step_s;
    const float* xrow = x + (size_t)(b * SS + sstep) * TXX;
    for (int i = tid; i < TXX; i += 256) xsr[i] = xrow[i];
    __syncthreads();
    float pk = 0.f;
    #pragma unroll
    for (int l = 0; l < FILT; ++l) pk = fmaf(xsr[tid + l], wt[l], pk);
    float d = y[(size_t)(b * SS + sstep) * TYY + tid] - pk;
    red[tid] = d * d;
    __syncthreads();
    for (int off = 128; off > 0; off >>= 1) {
        if (tid < off) red[tid] += red[tid + off];
        __syncthreads();
    }
    if (tid == 0) {
        float lossval = red[0] * (1.0f / TYY);
        float* loss_sum = (float*)(ctrs + 2);
        if (anyv) {
            atomicAdd(loss_sum, lossval);
            atomicAdd(&ctrs[1], 1);
        }
        __threadfence();
        int prev = atomicAdd(&ctrs[0], 1);
        if (prev == BB * NT - 1) {
            float s = atomicAdd(loss_sum, 0.0f);     // atomic read (device-coherent)
            int c = atomicAdd(&ctrs[1], 0);
            out0[0] = s / (float)(c > 0 ? c : 1);
        }
    }
}

extern "C" void kernel_launch(void* const* d_in, const int* in_sizes, int n_in,
                              void* d_out, int out_size, void* d_ws, size_t ws_size,
                              hipStream_t stream)
{
    const float* fps  = (const float*)d_in[0];
    const float* x    = (const float*)d_in[1];
    const float* y    = (const float*)d_in[2];
    const int* steps  = (const int*)d_in[3];
    const float* W1   = (const float*)d_in[4];
    const float* b1   = (const float*)d_in[5];
    const float* gamma= (const float*)d_in[6];
    const float* beta = (const float*)d_in[7];
    const float* W2   = (const float*)d_in[8];
    const float* b2   = (const float*)d_in[9];
    const float* Wq   = (const float*)d_in[10];
    const float* bq   = (const float*)d_in[11];
    const float* Wk   = (const float*)d_in[12];
    const float* bk   = (const float*)d_in[13];

    // Output f32 flat: [loss(1) | alpha(B*S*S) | e_orig(B*S*D)]
    float* out   = (float*)d_out;
    float* alpha = out + 1;
    float* e_out = out + 1 + (size_t)BB * SS * SS;

    // ws: [gram(80*1088) | ctrs(4 int) | q | kT]
    float* gram = (float*)d_ws;
    int*   ctrs = (int*)(gram + GRAMTOT);
    float* q    = (float*)(ctrs + 4);
    float* kT   = q + (size_t)BB * SS * DMODEL;

    const int C = 64, CS = SS / 64;

    hipLaunchKernelGGL(k_mlp, dim3(BB * SS / 8), dim3(256), 0, stream,
                       fps, W1, b1, gamma, beta, W2, b2, Wq, bq, Wk, bk,
                       e_out, q, kT, gram, ctrs);
    hipLaunchKernelGGL(k_attn, dim3(BB * (SS / 8)), dim3(256), 0, stream,
                       q, kT, alpha);
    hipLaunchKernelGGL(k_gpart, dim3(BB * C), dim3(256), 0, stream,
                       x, y, steps, alpha, gram, C, CS);
    hipLaunchKernelGGL(k_solve2, dim3(BB * NT), dim3(256), 0, stream,
                       x, y, steps, alpha, gram, ctrs, out);
}